// Round 8
// baseline (532.166 us; speedup 1.0000x reference)
//
#include <hip/hip_runtime.h>
#include <stdint.h>

typedef unsigned short u16;
typedef __attribute__((ext_vector_type(8))) short s16x8;
typedef __attribute__((ext_vector_type(4))) float f32x4;

// ---------- helpers ----------
__device__ __forceinline__ u16 f2bf(float f) {
  uint32_t u = __float_as_uint(f);
  uint32_t r = (u + 0x7FFFu + ((u >> 16) & 1u)) >> 16;   // RNE
  return (u16)r;
}

__device__ __forceinline__ void gll16(const void* g, void* lds) {
  __builtin_amdgcn_global_load_lds(
      (const __attribute__((address_space(1))) uint32_t*)g,
      (__attribute__((address_space(3))) uint32_t*)lds, 16, 0, 0);
}

// XCD-aware bijective swizzle (grids are multiples of 8)
__device__ __forceinline__ void xcd_swz(int& bx, int& by) {
  int gx = gridDim.x;
  int lin = blockIdx.y * gx + blockIdx.x;
  int cpx = (gx * gridDim.y) >> 3;
  int nl = (lin & 7) * cpx + (lin >> 3);
  bx = nl % gx;
  by = nl / gx;
}

// ---------- fp32 -> bf16 weight convert ----------
__global__ __launch_bounds__(256) void k_f2b(const float* __restrict__ src,
                                             u16* __restrict__ dst, int n) {
  int i = (blockIdx.x * 256 + threadIdx.x) * 4;
  if (i < n) {
    float4 v = *(const float4*)(src + i);
    ushort4 o;
    o.x = f2bf(v.x); o.y = f2bf(v.y); o.z = f2bf(v.z); o.w = f2bf(v.w);
    *(ushort4*)(dst + i) = o;
  }
}

// ---------- fused residual-mix + RMSNorm ----------
template <bool MIX>
__global__ __launch_bounds__(256) void k_rms(const float* __restrict__ X,
                                             const float* __restrict__ X0,
                                             const float* __restrict__ rmix,
                                             float* __restrict__ XMout,
                                             u16* __restrict__ Hout, float eps) {
  const int row = blockIdx.x, t = threadIdx.x;
  const size_t base = (size_t)row * 1024;
  float4 v;
  if (MIX) {
    float4 a = ((const float4*)(X + base))[t];
    float4 b = ((const float4*)(X0 + base))[t];
    float4 c0 = ((const float4*)rmix)[t];
    float4 c1 = ((const float4*)(rmix + 1024))[t];
    v.x = c0.x * a.x + c1.x * b.x;
    v.y = c0.y * a.y + c1.y * b.y;
    v.z = c0.z * a.z + c1.z * b.z;
    v.w = c0.w * a.w + c1.w * b.w;
  } else {
    v = ((const float4*)(X + base))[t];
  }
  float ss = v.x * v.x + v.y * v.y + v.z * v.z + v.w * v.w;
#pragma unroll
  for (int o = 32; o > 0; o >>= 1) ss += __shfl_xor(ss, o);
  __shared__ float red[4];
  if ((t & 63) == 0) red[t >> 6] = ss;
  __syncthreads();
  float tot = red[0] + red[1] + red[2] + red[3];
  float sc = rsqrtf(tot * (1.0f / 1024.0f) + eps);
  if (MIX) ((float4*)(XMout + base))[t] = v;
  ushort4 hv;
  hv.x = f2bf(v.x * sc); hv.y = f2bf(v.y * sc);
  hv.z = f2bf(v.z * sc); hv.w = f2bf(v.w * sc);
  ((ushort4*)(Hout + base))[t] = hv;
}

// ---------- chunked scan over S (float4 columns, 64-row chunks) ----------
// grid 256 = b(4) x chunk(64); thread t owns cols 4t..4t+3.
__global__ __launch_bounds__(256) void k_scan1(const float* __restrict__ P,
                                               float* __restrict__ CS) {
  int blk = blockIdx.x;
  int chunk = blk & 63, b = blk >> 6;
  const float4* p = (const float4*)(P + ((size_t)b * 4096 + chunk * 64) * 1024)
                    + threadIdx.x;
  float4 s = {0.f, 0.f, 0.f, 0.f};
#pragma unroll 8
  for (int i = 0; i < 64; ++i) {
    float4 v = p[(size_t)i * 256];
    s.x += v.x; s.y += v.y; s.z += v.z; s.w += v.w;
  }
  ((float4*)(CS + ((size_t)b * 64 + chunk) * 1024))[threadIdx.x] = s;
}

__global__ __launch_bounds__(256) void k_scan2(float* __restrict__ CS) {
  int idx = blockIdx.x * 256 + threadIdx.x;  // 4096 column-streams
  int b = idx >> 10, k = idx & 1023;
  float run = 0.f;
  for (int c = 0; c < 64; ++c) {
    size_t o = ((size_t)b * 64 + c) * 1024 + k;
    float v = CS[o];
    CS[o] = run;       // exclusive prefix
    run += v;
  }
}

// ---------- fused scan3 + rmsnorm(memory/denom) -> bf16 m ----------
// Per block: 64 rows x 1024 cols. run = exclusive chunk prefix; per row:
// run += p; y = run/denom; block-reduce sum(y^2); write bf16 y*rsqrt(...).
// The fp32 memory array is never materialized.
__global__ __launch_bounds__(256) void k_scan3f(const float* __restrict__ P,
                                                const float* __restrict__ CS,
                                                u16* __restrict__ Mout) {
  int blk = blockIdx.x;
  int chunk = blk & 63, b = blk >> 6;
  const int t = threadIdx.x, wid = t >> 6;
  __shared__ float red[2][4];
  float4 run = ((const float4*)(CS + ((size_t)b * 64 + chunk) * 1024))[t];
  const float4* p = (const float4*)(P + ((size_t)b * 4096 + chunk * 64) * 1024) + t;
  u16* mo = Mout + ((size_t)b * 4096 + chunk * 64) * 1024 + t * 4;
  for (int i = 0; i < 64; ++i) {
    float4 v = p[(size_t)i * 256];
    run.x += v.x; run.y += v.y; run.z += v.z; run.w += v.w;
    float inv = 1.0f / (float)(chunk * 64 + i + 1);
    float4 y;
    y.x = run.x * inv; y.y = run.y * inv; y.z = run.z * inv; y.w = run.w * inv;
    float ss = y.x * y.x + y.y * y.y + y.z * y.z + y.w * y.w;
#pragma unroll
    for (int o = 32; o > 0; o >>= 1) ss += __shfl_xor(ss, o);
    if ((t & 63) == 0) red[i & 1][wid] = ss;
    __syncthreads();
    float tot = red[i & 1][0] + red[i & 1][1] + red[i & 1][2] + red[i & 1][3];
    float sc = rsqrtf(tot * (1.0f / 1024.0f) + 1.1920929e-7f);
    ushort4 hv;
    hv.x = f2bf(y.x * sc); hv.y = f2bf(y.y * sc);
    hv.z = f2bf(y.z * sc); hv.w = f2bf(y.w * sc);
    *(ushort4*)(mo + (size_t)i * 1024) = hv;
  }
}

// ---------- dual-B GEMM: P = sigmoid(A@Wg^T) * (A@Wu^T)  (R3-proven) ----------
__global__ __launch_bounds__(256, 2) void gemm_dual(
    const u16* __restrict__ A, const u16* __restrict__ Bu,
    const u16* __restrict__ Bg, float* __restrict__ P, int K) {
  __shared__ __align__(16) u16 As[128 * 64];
  __shared__ __align__(16) u16 Us[64 * 64];
  __shared__ __align__(16) u16 Gs[64 * 64];
  const int t = threadIdx.x;
  const int lane = t & 63, wid = t >> 6;
  int bx, by;
  xcd_swz(bx, by);
  const int m0 = by * 128, n0 = bx * 64;
  const int wm = wid * 32;
  const int l15 = lane & 15, lhi = lane >> 4;

  size_t gA[4], gU[2];
#pragma unroll
  for (int i = 0; i < 4; ++i) {
    int j = i * 256 + t;
    int row = j >> 3;
    int k16 = (j & 7) ^ (row & 7);
    gA[i] = (size_t)(m0 + row) * K + k16 * 8;
  }
#pragma unroll
  for (int i = 0; i < 2; ++i) {
    int j = i * 256 + t;
    int row = j >> 3;
    int k16 = (j & 7) ^ (row & 7);
    gU[i] = (size_t)(n0 + row) * K + k16 * 8;
  }

  f32x4 au[2][4], ag[2][4];
#pragma unroll
  for (int mi = 0; mi < 2; ++mi)
#pragma unroll
    for (int ni = 0; ni < 4; ++ni) { au[mi][ni] = 0.0f; ag[mi][ni] = 0.0f; }

  for (int kb = 0; kb < K; kb += 64) {
#pragma unroll
    for (int i = 0; i < 4; ++i) {
      int j = i * 256 + t;
      gll16(A + gA[i] + kb, &As[j * 8]);
    }
#pragma unroll
    for (int i = 0; i < 2; ++i) {
      int j = i * 256 + t;
      gll16(Bu + gU[i] + kb, &Us[j * 8]);
      gll16(Bg + gU[i] + kb, &Gs[j * 8]);
    }
    __syncthreads();
#pragma unroll
    for (int kc = 0; kc < 2; ++kc) {
      s16x8 af[2], uf[4], gf[4];
#pragma unroll
      for (int mi = 0; mi < 2; ++mi) {
        int row = wm + mi * 16 + l15;
        int k16 = (kc * 4 + lhi) ^ (row & 7);
        af[mi] = *(const s16x8*)&As[row * 64 + k16 * 8];
      }
#pragma unroll
      for (int ni = 0; ni < 4; ++ni) {
        int row = ni * 16 + l15;
        int k16 = (kc * 4 + lhi) ^ (row & 7);
        uf[ni] = *(const s16x8*)&Us[row * 64 + k16 * 8];
        gf[ni] = *(const s16x8*)&Gs[row * 64 + k16 * 8];
      }
#pragma unroll
      for (int mi = 0; mi < 2; ++mi)
#pragma unroll
        for (int ni = 0; ni < 4; ++ni) {
          au[mi][ni] = __builtin_amdgcn_mfma_f32_16x16x32_bf16(
              af[mi], uf[ni], au[mi][ni], 0, 0, 0);
          ag[mi][ni] = __builtin_amdgcn_mfma_f32_16x16x32_bf16(
              af[mi], gf[ni], ag[mi][ni], 0, 0, 0);
        }
    }
    __syncthreads();
  }

#pragma unroll
  for (int mi = 0; mi < 2; ++mi) {
    int r0 = m0 + wm + mi * 16 + lhi * 4;
#pragma unroll
    for (int ni = 0; ni < 4; ++ni) {
      int c = n0 + ni * 16 + l15;
#pragma unroll
      for (int j = 0; j < 4; ++j) {
        float u = au[mi][ni][j], g = ag[mi][ni][j];
        P[(size_t)(r0 + j) * 1024 + c] = u / (1.0f + __expf(-g));
      }
    }
  }
}

// ---------- bf16 MFMA GEMM, 128x128 2-blocks/CU (R3-proven structure) ----------
// C[M,N](ldc) = A[M,K](lda) @ B[N,K](ldb)^T
// EPI 1: Cout(f32) = Cadd + colscale[c]*acc    (in-place Cadd==Cout ok)
// EPI 2: Cout(bf16) = relu(acc)^2
template <int EPI>
__global__ __launch_bounds__(256, 2) void gemm_bf16(
    const u16* __restrict__ A, const u16* __restrict__ Bw, void* __restrict__ Cout,
    const float* __restrict__ Cadd, const float* __restrict__ colscale,
    int K, int lda, int ldb, int ldc) {
  __shared__ __align__(16) u16 As[128 * 64];
  __shared__ __align__(16) u16 Bs[128 * 64];
  const int t = threadIdx.x;
  const int lane = t & 63, wid = t >> 6;
  int bx, by;
  xcd_swz(bx, by);
  const int m0 = by * 128, n0 = bx * 128;
  const int wm = (wid >> 1) * 64, wn = (wid & 1) * 64;
  const int l15 = lane & 15, lhi = lane >> 4;

  size_t gA[4], gB[4];
#pragma unroll
  for (int i = 0; i < 4; ++i) {
    int j = i * 256 + t;
    int row = j >> 3;
    int k16 = (j & 7) ^ (row & 7);
    gA[i] = (size_t)(m0 + row) * lda + k16 * 8;
    gB[i] = (size_t)(n0 + row) * ldb + k16 * 8;
  }

  f32x4 acc[4][4];
#pragma unroll
  for (int mi = 0; mi < 4; ++mi)
#pragma unroll
    for (int ni = 0; ni < 4; ++ni) acc[mi][ni] = 0.0f;

  for (int kb = 0; kb < K; kb += 64) {
#pragma unroll
    for (int i = 0; i < 4; ++i) {
      int j = i * 256 + t;
      gll16(A + gA[i] + kb, &As[j * 8]);
      gll16(Bw + gB[i] + kb, &Bs[j * 8]);
    }
    __syncthreads();
#pragma unroll
    for (int kc = 0; kc < 2; ++kc) {
      s16x8 af[4], bfr[4];
#pragma unroll
      for (int mi = 0; mi < 4; ++mi) {
        int row = wm + mi * 16 + l15;
        int k16 = (kc * 4 + lhi) ^ (row & 7);
        af[mi] = *(const s16x8*)&As[row * 64 + k16 * 8];
      }
#pragma unroll
      for (int ni = 0; ni < 4; ++ni) {
        int row = wn + ni * 16 + l15;
        int k16 = (kc * 4 + lhi) ^ (row & 7);
        bfr[ni] = *(const s16x8*)&Bs[row * 64 + k16 * 8];
      }
#pragma unroll
      for (int mi = 0; mi < 4; ++mi)
#pragma unroll
        for (int ni = 0; ni < 4; ++ni)
          acc[mi][ni] = __builtin_amdgcn_mfma_f32_16x16x32_bf16(
              af[mi], bfr[ni], acc[mi][ni], 0, 0, 0);
    }
    __syncthreads();
  }

#pragma unroll
  for (int mi = 0; mi < 4; ++mi) {
    int r0 = m0 + wm + mi * 16 + lhi * 4;
#pragma unroll
    for (int ni = 0; ni < 4; ++ni) {
      int c = n0 + wn + ni * 16 + l15;
      float cs = (EPI == 1) ? colscale[c] : 0.f;
#pragma unroll
      for (int j = 0; j < 4; ++j) {
        size_t idx = (size_t)(r0 + j) * ldc + c;
        float v = acc[mi][ni][j];
        if (EPI == 1) {
          ((float*)Cout)[idx] = Cadd[idx] + cs * v;
        } else {
          float rv = fmaxf(v, 0.f);
          ((u16*)Cout)[idx] = f2bf(rv * rv);
        }
      }
    }
  }
}

// ---------- launch ----------
extern "C" void kernel_launch(void* const* d_in, const int* in_sizes, int n_in,
                              void* d_out, int out_size, void* d_ws, size_t ws_size,
                              hipStream_t stream) {
  const float* x = (const float*)d_in[0];
  const float* x0 = (const float*)d_in[1];
  const float* Wu = (const float*)d_in[2];
  const float* Wg = (const float*)d_in[3];
  const float* Wo = (const float*)d_in[4];
  const float* Wfc = (const float*)d_in[5];
  const float* Wpj = (const float*)d_in[6];
  const float* mmix = (const float*)d_in[7];
  const float* mscale = (const float*)d_in[8];
  const float* rmix = (const float*)d_in[9];
  float* out = (float*)d_out;

  const int M = 16384;  // B*S
  const size_t MiB = 1024 * 1024;

  // workspace layout (base 151 MiB; fullR2 single-pass proj needs 182 MiB)
  char* ws = (char*)d_ws;
  u16* WuB = (u16*)ws;   ws += 2 * MiB;
  u16* WgB = (u16*)ws;   ws += 2 * MiB;
  u16* WoB = (u16*)ws;   ws += 2 * MiB;
  u16* WfcB = (u16*)ws;  ws += 8 * MiB;
  u16* WpjB = (u16*)ws;  ws += 8 * MiB;
  u16* h = (u16*)ws;     ws += 32 * MiB;                  // h then h2
  char* pool = ws;                                        // 54 MiB in
  float* P = (float*)pool;                                // 64 MiB (gated p)
  float* CS = (float*)(pool + 64 * MiB);                  // 1 MiB chunk sums
  u16* mB = (u16*)(pool + 65 * MiB);                      // 32 MiB normalized mem
  u16* R2 = (u16*)pool;                                   // aliases dead P/CS/mB
  float* xm = out;                                        // xm/x2 lives in d_out

  const bool fullR2 = ws_size >= 182 * MiB;  // R2 = M x 4096 bf16 = 128 MiB

  // weights -> bf16
  k_f2b<<<1024, 256, 0, stream>>>(Wu, WuB, 1024 * 1024);
  k_f2b<<<1024, 256, 0, stream>>>(Wg, WgB, 1024 * 1024);
  k_f2b<<<1024, 256, 0, stream>>>(Wo, WoB, 1024 * 1024);
  k_f2b<<<4096, 256, 0, stream>>>(Wfc, WfcB, 4096 * 1024);
  k_f2b<<<4096, 256, 0, stream>>>(Wpj, WpjB, 4096 * 1024);

  // residual mix + rmsnorm: xm (=out), h
  k_rms<true><<<M, 256, 0, stream>>>(x, x0, rmix, xm, h, 1e-6f);

  // p = sigmoid(h@Wg^T) * (h@Wu^T)
  gemm_dual<<<dim3(16, 128), 256, 0, stream>>>(h, WuB, WgB, P, 1024);

  // memory = cumsum_S(p); m = bf16(rmsnorm(memory/denom))  (fused scan)
  k_scan1<<<256, 256, 0, stream>>>(P, CS);
  k_scan2<<<16, 256, 0, stream>>>(CS);
  k_scan3f<<<256, 256, 0, stream>>>(P, CS, mB);

  // x2 = xm + mmix * (m @ Wo^T)   (in-place in d_out)
  gemm_bf16<1><<<dim3(8, 128), 256, 0, stream>>>(mB, WoB, xm, xm, mmix,
                                                 1024, 1024, 1024, 1024);
  // h2 = bf16(rmsnorm(x2))
  k_rms<false><<<M, 256, 0, stream>>>(xm, nullptr, nullptr, nullptr, h, 1e-6f);

  if (fullR2) {
    // R2(full M x 4096) = relu(h2 @ Wfc^T)^2 in ONE dispatch, then K=4096 proj
    gemm_bf16<2><<<dim3(32, 128), 256, 0, stream>>>(
        h, WfcB, R2, nullptr, nullptr, 1024, 1024, 1024, 4096);
    gemm_bf16<1><<<dim3(8, 128), 256, 0, stream>>>(
        R2, WpjB, out, out, mscale, 4096, 4096, 4096, 1024);
  } else {
    // MLP in two HID halves; R2 buffer (M x 2048 bf16) reused
    for (int c = 0; c < 2; ++c) {
      gemm_bf16<2><<<dim3(16, 128), 256, 0, stream>>>(
          h, WfcB + (size_t)c * 2048 * 1024, R2, nullptr, nullptr,
          1024, 1024, 1024, 2048);
      gemm_bf16<1><<<dim3(8, 128), 256, 0, stream>>>(
          R2, WpjB + (size_t)c * 2048, out, out, mscale,
          2048, 2048, 4096, 1024);
    }
  }
}

// Round 9
// 520.334 us; speedup vs baseline: 1.0227x; 1.0227x over previous
//
#include <hip/hip_runtime.h>
#include <stdint.h>

typedef unsigned short u16;
typedef __attribute__((ext_vector_type(8))) short s16x8;
typedef __attribute__((ext_vector_type(4))) float f32x4;

// ---------- helpers ----------
__device__ __forceinline__ u16 f2bf(float f) {
  uint32_t u = __float_as_uint(f);
  uint32_t r = (u + 0x7FFFu + ((u >> 16) & 1u)) >> 16;   // RNE
  return (u16)r;
}

__device__ __forceinline__ void gll16(const void* g, void* lds) {
  __builtin_amdgcn_global_load_lds(
      (const __attribute__((address_space(1))) uint32_t*)g,
      (__attribute__((address_space(3))) uint32_t*)lds, 16, 0, 0);
}

// XCD-aware bijective swizzle (grids are multiples of 8)
__device__ __forceinline__ void xcd_swz(int& bx, int& by) {
  int gx = gridDim.x;
  int lin = blockIdx.y * gx + blockIdx.x;
  int cpx = (gx * gridDim.y) >> 3;
  int nl = (lin & 7) * cpx + (lin >> 3);
  bx = nl % gx;
  by = nl / gx;
}

// ---------- fp32 -> bf16 weight convert ----------
__global__ __launch_bounds__(256) void k_f2b(const float* __restrict__ src,
                                             u16* __restrict__ dst, int n) {
  int i = (blockIdx.x * 256 + threadIdx.x) * 4;
  if (i < n) {
    float4 v = *(const float4*)(src + i);
    ushort4 o;
    o.x = f2bf(v.x); o.y = f2bf(v.y); o.z = f2bf(v.z); o.w = f2bf(v.w);
    *(ushort4*)(dst + i) = o;
  }
}

// ---------- fused residual-mix + RMSNorm ----------
template <bool MIX>
__global__ __launch_bounds__(256) void k_rms(const float* __restrict__ X,
                                             const float* __restrict__ X0,
                                             const float* __restrict__ rmix,
                                             float* __restrict__ XMout,
                                             u16* __restrict__ Hout, float eps) {
  const int row = blockIdx.x, t = threadIdx.x;
  const size_t base = (size_t)row * 1024;
  float4 v;
  if (MIX) {
    float4 a = ((const float4*)(X + base))[t];
    float4 b = ((const float4*)(X0 + base))[t];
    float4 c0 = ((const float4*)rmix)[t];
    float4 c1 = ((const float4*)(rmix + 1024))[t];
    v.x = c0.x * a.x + c1.x * b.x;
    v.y = c0.y * a.y + c1.y * b.y;
    v.z = c0.z * a.z + c1.z * b.z;
    v.w = c0.w * a.w + c1.w * b.w;
  } else {
    v = ((const float4*)(X + base))[t];
  }
  float ss = v.x * v.x + v.y * v.y + v.z * v.z + v.w * v.w;
#pragma unroll
  for (int o = 32; o > 0; o >>= 1) ss += __shfl_xor(ss, o);
  __shared__ float red[4];
  if ((t & 63) == 0) red[t >> 6] = ss;
  __syncthreads();
  float tot = red[0] + red[1] + red[2] + red[3];
  float sc = rsqrtf(tot * (1.0f / 1024.0f) + eps);
  if (MIX) ((float4*)(XMout + base))[t] = v;
  ushort4 hv;
  hv.x = f2bf(v.x * sc); hv.y = f2bf(v.y * sc);
  hv.z = f2bf(v.z * sc); hv.w = f2bf(v.w * sc);
  ((ushort4*)(Hout + base))[t] = hv;
}

// ---------- chunked scan over S (16-row chunks) ----------
// grid 1024 = b(4) x chunk(256); 256 threads, thread t owns cols 4t..4t+3.
__global__ __launch_bounds__(256) void k_scan1(const float* __restrict__ P,
                                               float* __restrict__ CS) {
  int blk = blockIdx.x;
  int chunk = blk & 255, b = blk >> 8;
  const float4* p = (const float4*)(P + ((size_t)b * 4096 + chunk * 16) * 1024)
                    + threadIdx.x;
  float4 s = {0.f, 0.f, 0.f, 0.f};
#pragma unroll
  for (int i = 0; i < 16; ++i) {
    float4 v = p[(size_t)i * 256];
    s.x += v.x; s.y += v.y; s.z += v.z; s.w += v.w;
  }
  ((float4*)(CS + ((size_t)b * 256 + chunk) * 1024))[threadIdx.x] = s;
}

__global__ __launch_bounds__(256) void k_scan2(float* __restrict__ CS) {
  int idx = blockIdx.x * 256 + threadIdx.x;  // 4096 column-streams
  int b = idx >> 10, k = idx & 1023;
  float run = 0.f;
  for (int c = 0; c < 256; ++c) {
    size_t o = ((size_t)b * 256 + c) * 1024 + k;
    float v = CS[o];
    CS[o] = run;       // exclusive prefix
    run += v;
  }
}

// ---------- fused scan3 + rmsnorm(memory/denom) -> bf16 m  (wave-only) ----------
// grid 1024 = b(4) x chunk(256); 64 threads; lane owns 16 cols (4x float4).
// Row reduction = 6 shfl_xor steps; NO __syncthreads, NO LDS.
__global__ __launch_bounds__(64) void k_scan3f(const float* __restrict__ P,
                                               const float* __restrict__ CS,
                                               u16* __restrict__ Mout) {
  int blk = blockIdx.x;
  int chunk = blk & 255, b = blk >> 8;
  const int t = threadIdx.x;
  const float4* cs4 = (const float4*)(CS + ((size_t)b * 256 + chunk) * 1024);
  float4 run[4];
#pragma unroll
  for (int q = 0; q < 4; ++q) run[q] = cs4[q * 64 + t];
  const float4* p4 = (const float4*)(P + ((size_t)b * 4096 + chunk * 16) * 1024);
  u16* mo = Mout + ((size_t)b * 4096 + chunk * 16) * 1024;
  const int rowbase = chunk * 16;
#pragma unroll 2
  for (int i = 0; i < 16; ++i) {
    float4 v[4];
#pragma unroll
    for (int q = 0; q < 4; ++q) v[q] = p4[(size_t)i * 256 + q * 64 + t];
    const float inv = 1.0f / (float)(rowbase + i + 1);
    float4 y[4];
    float ss = 0.f;
#pragma unroll
    for (int q = 0; q < 4; ++q) {
      run[q].x += v[q].x; run[q].y += v[q].y;
      run[q].z += v[q].z; run[q].w += v[q].w;
      y[q].x = run[q].x * inv; y[q].y = run[q].y * inv;
      y[q].z = run[q].z * inv; y[q].w = run[q].w * inv;
      ss += y[q].x * y[q].x + y[q].y * y[q].y
          + y[q].z * y[q].z + y[q].w * y[q].w;
    }
#pragma unroll
    for (int o = 32; o > 0; o >>= 1) ss += __shfl_xor(ss, o);
    float sc = rsqrtf(ss * (1.0f / 1024.0f) + 1.1920929e-7f);
#pragma unroll
    for (int q = 0; q < 4; ++q) {
      ushort4 hv;
      hv.x = f2bf(y[q].x * sc); hv.y = f2bf(y[q].y * sc);
      hv.z = f2bf(y[q].z * sc); hv.w = f2bf(y[q].w * sc);
      *(ushort4*)(mo + (size_t)i * 1024 + (q * 64 + t) * 4) = hv;
    }
  }
}

// ---------- dual-B GEMM: P = sigmoid(A@Wg^T) * (A@Wu^T)  (R3-proven) ----------
__global__ __launch_bounds__(256, 2) void gemm_dual(
    const u16* __restrict__ A, const u16* __restrict__ Bu,
    const u16* __restrict__ Bg, float* __restrict__ P, int K) {
  __shared__ __align__(16) u16 As[128 * 64];
  __shared__ __align__(16) u16 Us[64 * 64];
  __shared__ __align__(16) u16 Gs[64 * 64];
  const int t = threadIdx.x;
  const int lane = t & 63, wid = t >> 6;
  int bx, by;
  xcd_swz(bx, by);
  const int m0 = by * 128, n0 = bx * 64;
  const int wm = wid * 32;
  const int l15 = lane & 15, lhi = lane >> 4;

  size_t gA[4], gU[2];
#pragma unroll
  for (int i = 0; i < 4; ++i) {
    int j = i * 256 + t;
    int row = j >> 3;
    int k16 = (j & 7) ^ (row & 7);
    gA[i] = (size_t)(m0 + row) * K + k16 * 8;
  }
#pragma unroll
  for (int i = 0; i < 2; ++i) {
    int j = i * 256 + t;
    int row = j >> 3;
    int k16 = (j & 7) ^ (row & 7);
    gU[i] = (size_t)(n0 + row) * K + k16 * 8;
  }

  f32x4 au[2][4], ag[2][4];
#pragma unroll
  for (int mi = 0; mi < 2; ++mi)
#pragma unroll
    for (int ni = 0; ni < 4; ++ni) { au[mi][ni] = 0.0f; ag[mi][ni] = 0.0f; }

  for (int kb = 0; kb < K; kb += 64) {
#pragma unroll
    for (int i = 0; i < 4; ++i) {
      int j = i * 256 + t;
      gll16(A + gA[i] + kb, &As[j * 8]);
    }
#pragma unroll
    for (int i = 0; i < 2; ++i) {
      int j = i * 256 + t;
      gll16(Bu + gU[i] + kb, &Us[j * 8]);
      gll16(Bg + gU[i] + kb, &Gs[j * 8]);
    }
    __syncthreads();
#pragma unroll
    for (int kc = 0; kc < 2; ++kc) {
      s16x8 af[2], uf[4], gf[4];
#pragma unroll
      for (int mi = 0; mi < 2; ++mi) {
        int row = wm + mi * 16 + l15;
        int k16 = (kc * 4 + lhi) ^ (row & 7);
        af[mi] = *(const s16x8*)&As[row * 64 + k16 * 8];
      }
#pragma unroll
      for (int ni = 0; ni < 4; ++ni) {
        int row = ni * 16 + l15;
        int k16 = (kc * 4 + lhi) ^ (row & 7);
        uf[ni] = *(const s16x8*)&Us[row * 64 + k16 * 8];
        gf[ni] = *(const s16x8*)&Gs[row * 64 + k16 * 8];
      }
#pragma unroll
      for (int mi = 0; mi < 2; ++mi)
#pragma unroll
        for (int ni = 0; ni < 4; ++ni) {
          au[mi][ni] = __builtin_amdgcn_mfma_f32_16x16x32_bf16(
              af[mi], uf[ni], au[mi][ni], 0, 0, 0);
          ag[mi][ni] = __builtin_amdgcn_mfma_f32_16x16x32_bf16(
              af[mi], gf[ni], ag[mi][ni], 0, 0, 0);
        }
    }
    __syncthreads();
  }

#pragma unroll
  for (int mi = 0; mi < 2; ++mi) {
    int r0 = m0 + wm + mi * 16 + lhi * 4;
#pragma unroll
    for (int ni = 0; ni < 4; ++ni) {
      int c = n0 + ni * 16 + l15;
#pragma unroll
      for (int j = 0; j < 4; ++j) {
        float u = au[mi][ni][j], g = ag[mi][ni][j];
        P[(size_t)(r0 + j) * 1024 + c] = u / (1.0f + __expf(-g));
      }
    }
  }
}

// ---------- bf16 MFMA GEMM, 128x128 2-blocks/CU (R3-proven structure) ----------
// C[M,N](ldc) = A[M,K](lda) @ B[N,K](ldb)^T
// EPI 1: Cout(f32) = Cadd + colscale[c]*acc    (in-place Cadd==Cout ok)
// EPI 2: Cout(bf16) = relu(acc)^2
template <int EPI>
__global__ __launch_bounds__(256, 2) void gemm_bf16(
    const u16* __restrict__ A, const u16* __restrict__ Bw, void* __restrict__ Cout,
    const float* __restrict__ Cadd, const float* __restrict__ colscale,
    int K, int lda, int ldb, int ldc) {
  __shared__ __align__(16) u16 As[128 * 64];
  __shared__ __align__(16) u16 Bs[128 * 64];
  const int t = threadIdx.x;
  const int lane = t & 63, wid = t >> 6;
  int bx, by;
  xcd_swz(bx, by);
  const int m0 = by * 128, n0 = bx * 128;
  const int wm = (wid >> 1) * 64, wn = (wid & 1) * 64;
  const int l15 = lane & 15, lhi = lane >> 4;

  size_t gA[4], gB[4];
#pragma unroll
  for (int i = 0; i < 4; ++i) {
    int j = i * 256 + t;
    int row = j >> 3;
    int k16 = (j & 7) ^ (row & 7);
    gA[i] = (size_t)(m0 + row) * lda + k16 * 8;
    gB[i] = (size_t)(n0 + row) * ldb + k16 * 8;
  }

  f32x4 acc[4][4];
#pragma unroll
  for (int mi = 0; mi < 4; ++mi)
#pragma unroll
    for (int ni = 0; ni < 4; ++ni) acc[mi][ni] = 0.0f;

  for (int kb = 0; kb < K; kb += 64) {
#pragma unroll
    for (int i = 0; i < 4; ++i) {
      int j = i * 256 + t;
      gll16(A + gA[i] + kb, &As[j * 8]);
      gll16(Bw + gB[i] + kb, &Bs[j * 8]);
    }
    __syncthreads();
#pragma unroll
    for (int kc = 0; kc < 2; ++kc) {
      s16x8 af[4], bfr[4];
#pragma unroll
      for (int mi = 0; mi < 4; ++mi) {
        int row = wm + mi * 16 + l15;
        int k16 = (kc * 4 + lhi) ^ (row & 7);
        af[mi] = *(const s16x8*)&As[row * 64 + k16 * 8];
      }
#pragma unroll
      for (int ni = 0; ni < 4; ++ni) {
        int row = wn + ni * 16 + l15;
        int k16 = (kc * 4 + lhi) ^ (row & 7);
        bfr[ni] = *(const s16x8*)&Bs[row * 64 + k16 * 8];
      }
#pragma unroll
      for (int mi = 0; mi < 4; ++mi)
#pragma unroll
        for (int ni = 0; ni < 4; ++ni)
          acc[mi][ni] = __builtin_amdgcn_mfma_f32_16x16x32_bf16(
              af[mi], bfr[ni], acc[mi][ni], 0, 0, 0);
    }
    __syncthreads();
  }

#pragma unroll
  for (int mi = 0; mi < 4; ++mi) {
    int r0 = m0 + wm + mi * 16 + lhi * 4;
#pragma unroll
    for (int ni = 0; ni < 4; ++ni) {
      int c = n0 + wn + ni * 16 + l15;
      float cs = (EPI == 1) ? colscale[c] : 0.f;
#pragma unroll
      for (int j = 0; j < 4; ++j) {
        size_t idx = (size_t)(r0 + j) * ldc + c;
        float v = acc[mi][ni][j];
        if (EPI == 1) {
          ((float*)Cout)[idx] = Cadd[idx] + cs * v;
        } else {
          float rv = fmaxf(v, 0.f);
          ((u16*)Cout)[idx] = f2bf(rv * rv);
        }
      }
    }
  }
}

// ---------- launch ----------
extern "C" void kernel_launch(void* const* d_in, const int* in_sizes, int n_in,
                              void* d_out, int out_size, void* d_ws, size_t ws_size,
                              hipStream_t stream) {
  const float* x = (const float*)d_in[0];
  const float* x0 = (const float*)d_in[1];
  const float* Wu = (const float*)d_in[2];
  const float* Wg = (const float*)d_in[3];
  const float* Wo = (const float*)d_in[4];
  const float* Wfc = (const float*)d_in[5];
  const float* Wpj = (const float*)d_in[6];
  const float* mmix = (const float*)d_in[7];
  const float* mscale = (const float*)d_in[8];
  const float* rmix = (const float*)d_in[9];
  float* out = (float*)d_out;

  const int M = 16384;  // B*S
  const size_t MiB = 1024 * 1024;

  // workspace layout (base 154 MiB; fullR2 single-pass proj needs 182 MiB)
  char* ws = (char*)d_ws;
  u16* WuB = (u16*)ws;   ws += 2 * MiB;
  u16* WgB = (u16*)ws;   ws += 2 * MiB;
  u16* WoB = (u16*)ws;   ws += 2 * MiB;
  u16* WfcB = (u16*)ws;  ws += 8 * MiB;
  u16* WpjB = (u16*)ws;  ws += 8 * MiB;
  u16* h = (u16*)ws;     ws += 32 * MiB;                  // h then h2
  char* pool = ws;                                        // 54 MiB in
  float* P = (float*)pool;                                // 64 MiB (gated p)
  float* CS = (float*)(pool + 64 * MiB);                  // 4 MiB chunk sums
  u16* mB = (u16*)(pool + 68 * MiB);                      // 32 MiB normalized mem
  u16* R2 = (u16*)pool;                                   // aliases dead P/CS/mB
  float* xm = out;                                        // xm/x2 lives in d_out

  const bool fullR2 = ws_size >= 182 * MiB;  // R2 = M x 4096 bf16 = 128 MiB

  // weights -> bf16
  k_f2b<<<1024, 256, 0, stream>>>(Wu, WuB, 1024 * 1024);
  k_f2b<<<1024, 256, 0, stream>>>(Wg, WgB, 1024 * 1024);
  k_f2b<<<1024, 256, 0, stream>>>(Wo, WoB, 1024 * 1024);
  k_f2b<<<4096, 256, 0, stream>>>(Wfc, WfcB, 4096 * 1024);
  k_f2b<<<4096, 256, 0, stream>>>(Wpj, WpjB, 4096 * 1024);

  // residual mix + rmsnorm: xm (=out), h
  k_rms<true><<<M, 256, 0, stream>>>(x, x0, rmix, xm, h, 1e-6f);

  // p = sigmoid(h@Wg^T) * (h@Wu^T)
  gemm_dual<<<dim3(16, 128), 256, 0, stream>>>(h, WuB, WgB, P, 1024);

  // memory = cumsum_S(p); m = bf16(rmsnorm(memory/denom))  (fused, wave-only)
  k_scan1<<<1024, 256, 0, stream>>>(P, CS);
  k_scan2<<<16, 256, 0, stream>>>(CS);
  k_scan3f<<<1024, 64, 0, stream>>>(P, CS, mB);

  // x2 = xm + mmix * (m @ Wo^T)   (in-place in d_out)
  gemm_bf16<1><<<dim3(8, 128), 256, 0, stream>>>(mB, WoB, xm, xm, mmix,
                                                 1024, 1024, 1024, 1024);
  // h2 = bf16(rmsnorm(x2))
  k_rms<false><<<M, 256, 0, stream>>>(xm, nullptr, nullptr, nullptr, h, 1e-6f);

  if (fullR2) {
    // R2(full M x 4096) = relu(h2 @ Wfc^T)^2 in ONE dispatch, then K=4096 proj
    gemm_bf16<2><<<dim3(32, 128), 256, 0, stream>>>(
        h, WfcB, R2, nullptr, nullptr, 1024, 1024, 1024, 4096);
    gemm_bf16<1><<<dim3(8, 128), 256, 0, stream>>>(
        R2, WpjB, out, out, mscale, 4096, 4096, 4096, 1024);
  } else {
    // MLP in two HID halves; R2 buffer (M x 2048 bf16) reused
    for (int c = 0; c < 2; ++c) {
      gemm_bf16<2><<<dim3(16, 128), 256, 0, stream>>>(
          h, WfcB + (size_t)c * 2048 * 1024, R2, nullptr, nullptr,
          1024, 1024, 1024, 2048);
      gemm_bf16<1><<<dim3(8, 128), 256, 0, stream>>>(
          R2, WpjB + (size_t)c * 2048, out, out, mscale,
          2048, 2048, 4096, 1024);
    }
  }
}